// Round 5
// baseline (378.873 us; speedup 1.0000x reference)
//
#include <hip/hip_runtime.h>
#include <stdint.h>

// Problem constants (fixed by setup_inputs; all tensors f32)
#define B_ROWS 4096
#define D_IN   784
#define H_DIM  800
#define D_OUT  10
#define T_SIM  32
#define N_ELEM (B_ROWS * D_IN)   // 3211264
#define CAP    448               // spiking-list cap/row (mean ~376, sd ~14)

// ---------------------------------------------------------------------------
// Bit-exact JAX threefry2x32 (key = PRNGKey(42) = {0, 42})
// ---------------------------------------------------------------------------
__device__ __forceinline__ void threefry2x32(uint32_t k0, uint32_t k1,
                                             uint32_t& x0, uint32_t& x1) {
  uint32_t ks0 = k0, ks1 = k1, ks2 = k0 ^ k1 ^ 0x1BD11BDAu;
  x0 += ks0; x1 += ks1;
#define TF_RND(r) { x0 += x1; x1 = (x1 << (r)) | (x1 >> (32 - (r))); x1 ^= x0; }
  TF_RND(13) TF_RND(15) TF_RND(26) TF_RND(6)
  x0 += ks1; x1 += ks2 + 1u;
  TF_RND(17) TF_RND(29) TF_RND(16) TF_RND(24)
  x0 += ks2; x1 += ks0 + 2u;
  TF_RND(13) TF_RND(15) TF_RND(26) TF_RND(6)
  x0 += ks0; x1 += ks1 + 3u;
  TF_RND(17) TF_RND(29) TF_RND(16) TF_RND(24)
  x0 += ks1; x1 += ks2 + 4u;
  TF_RND(13) TF_RND(15) TF_RND(26) TF_RND(6)
  x0 += ks2; x1 += ks0 + 5u;
#undef TF_RND
}

// ---------------------------------------------------------------------------
// K0a: x_fixed computed DIRECTLY in transposed layout xfT[k][m] (k-major).
// Same threefry counter i = m*784 + k -> bit-identical values to before.
// Writes coalesced (lanes vary m at fixed k); x reads are lane-private
// row segments (each lane streams 16 consecutive k of its own row, L1-hot).
// grid (16 m-blocks, 49 k-chunks), 256 thr.
// ---------------------------------------------------------------------------
__global__ __launch_bounds__(256) void gen_xfixed_T(const float* __restrict__ x,
                                                    float* __restrict__ xfT) {
  const int m = blockIdx.x * 256 + threadIdx.x;   // 0..4095
  const int kb = blockIdx.y * 16;                 // 0,16,..,768
#pragma unroll 1
  for (int kk = 0; kk < 16; ++kk) {
    const int k = kb + kk;
    const int i = m * D_IN + k;
    uint32_t c0 = 0u, c1 = (uint32_t)i;
    threefry2x32(0u, 42u, c0, c1);
    uint32_t bits = c0 ^ c1;
    float u = __uint_as_float((bits >> 9) | 0x3F800000u) - 1.0f;
    xfT[(size_t)k * B_ROWS + m] = (u < x[i]) ? 1.0f : 0.0f;
  }
}

// K0b: W1T[k][h] = W1[h][k] — bit-exact copy, 2.5 MB. Coalesced writes.
__global__ __launch_bounds__(256) void transpose_w1(const float* __restrict__ W1,
                                                    float* __restrict__ W1T) {
  const int idx = blockIdx.x * 256 + threadIdx.x;   // over k*800+h
  if (idx >= D_IN * H_DIM) return;
  const int k = idx / H_DIM;
  const int h = idx - k * H_DIM;
  W1T[idx] = W1[h * D_IN + k];
}

// ---------------------------------------------------------------------------
// K1 (R5): register-pipelined global-direct GEMM.  ZERO LDS, ZERO barriers.
// Evidence trail: R4's LDS-staged 64x64 = 177 us with VALUBusy 43% and
// 2.6M bank-conflict cycles — LDS transpose machinery is the overhead.
// With xfT/W1T (k-major), fragments are contiguous: per kk each thread does
// 2 coalesced global dwordx4 (A: 4 m, B: 4 h; 16-way broadcast within wave,
// L1/L2-served — per-block B set 4 KB/tile) + 16 ascending-k FMAs.
// Ping-pong 4-kk register pipeline (named vars, no runtime indexing, no
// moves); ~110 VGPR, NO min-occupancy launch bound (R3's spill was caused
// by __launch_bounds__(64,3) capping VGPR at 84).
// Exactness: per output single f32 acc, strict ascending-k fma chain,
// identical epilogue -> bit-identical to R4 (absmax 0.0).
// ---------------------------------------------------------------------------
__global__ __launch_bounds__(256) void gemm_masks(const float* __restrict__ xfT,
                                                  const float* __restrict__ W1T,
                                                  const float* __restrict__ b1,
                                                  uint32_t* __restrict__ mb) {
  const int t  = threadIdx.x;            // 0..255
  const int tx = t & 15, ty = t >> 4;
  const int m0   = blockIdx.y * 64;
  const int n0   = blockIdx.x * 64;
  const int mBase = m0 + ty * 4;         // 4 consecutive m
  const int hOut  = n0 + tx * 4;         // 4 consecutive h
  const bool bOK  = (hOut < H_DIM);
  const float* pA = xfT + mBase;                    // + k*4096
  const float* pB = W1T + (bOK ? hOut : 0);         // + k*800

  float acc[4][4] = {};

#define LDG4(d, base) d = *(const float4*)(base)
#define FMA16(AV, BV)                                            \
  { acc[0][0] = __builtin_fmaf(AV.x, BV.x, acc[0][0]);           \
    acc[0][1] = __builtin_fmaf(AV.x, BV.y, acc[0][1]);           \
    acc[0][2] = __builtin_fmaf(AV.x, BV.z, acc[0][2]);           \
    acc[0][3] = __builtin_fmaf(AV.x, BV.w, acc[0][3]);           \
    acc[1][0] = __builtin_fmaf(AV.y, BV.x, acc[1][0]);           \
    acc[1][1] = __builtin_fmaf(AV.y, BV.y, acc[1][1]);           \
    acc[1][2] = __builtin_fmaf(AV.y, BV.z, acc[1][2]);           \
    acc[1][3] = __builtin_fmaf(AV.y, BV.w, acc[1][3]);           \
    acc[2][0] = __builtin_fmaf(AV.z, BV.x, acc[2][0]);           \
    acc[2][1] = __builtin_fmaf(AV.z, BV.y, acc[2][1]);           \
    acc[2][2] = __builtin_fmaf(AV.z, BV.z, acc[2][2]);           \
    acc[2][3] = __builtin_fmaf(AV.z, BV.w, acc[2][3]);           \
    acc[3][0] = __builtin_fmaf(AV.w, BV.x, acc[3][0]);           \
    acc[3][1] = __builtin_fmaf(AV.w, BV.y, acc[3][1]);           \
    acc[3][2] = __builtin_fmaf(AV.w, BV.z, acc[3][2]);           \
    acc[3][3] = __builtin_fmaf(AV.w, BV.w, acc[3][3]); }

  float4 ca0, ca1, ca2, ca3, cb0, cb1, cb2, cb3;   // current 4-kk group
  float4 na0, na1, na2, na3, nb0, nb1, nb2, nb3;   // next 4-kk group

  // group g covers k = 4g..4g+3; 196 groups total (784 = 4*196)
  LDG4(ca0, pA + 0 * B_ROWS);  LDG4(cb0, pB + 0 * H_DIM);
  LDG4(ca1, pA + 1 * B_ROWS);  LDG4(cb1, pB + 1 * H_DIM);
  LDG4(ca2, pA + 2 * B_ROWS);  LDG4(cb2, pB + 2 * H_DIM);
  LDG4(ca3, pA + 3 * B_ROWS);  LDG4(cb3, pB + 3 * H_DIM);
  const float* qA = pA + 4 * B_ROWS;   // prefetch cursor (group 1)
  const float* qB = pB + 4 * H_DIM;

#define PREF(a0, a1, a2, a3, b0, b1, b2, b3)                     \
  { LDG4(a0, qA + 0 * B_ROWS);  LDG4(b0, qB + 0 * H_DIM);        \
    LDG4(a1, qA + 1 * B_ROWS);  LDG4(b1, qB + 1 * H_DIM);        \
    LDG4(a2, qA + 2 * B_ROWS);  LDG4(b2, qB + 2 * H_DIM);        \
    LDG4(a3, qA + 3 * B_ROWS);  LDG4(b3, qB + 3 * H_DIM);        \
    qA += 4 * B_ROWS;  qB += 4 * H_DIM; }
#define FMA4G(a0, a1, a2, a3, b0, b1, b2, b3)                    \
  { FMA16(a0, b0) FMA16(a1, b1) FMA16(a2, b2) FMA16(a3, b3) }

  // consume groups 0..193 in ping-pong pairs (97 pairs), then 194, 195
#pragma unroll 1
  for (int p = 0; p < 97; ++p) {
    PREF(na0, na1, na2, na3, nb0, nb1, nb2, nb3);   // load group 2p+1
    FMA4G(ca0, ca1, ca2, ca3, cb0, cb1, cb2, cb3);  // consume group 2p
    PREF(ca0, ca1, ca2, ca3, cb0, cb1, cb2, cb3);   // load group 2p+2
    FMA4G(na0, na1, na2, na3, nb0, nb1, nb2, nb3);  // consume group 2p+1
  }
  PREF(na0, na1, na2, na3, nb0, nb1, nb2, nb3);     // load group 195 (last)
  FMA4G(ca0, ca1, ca2, ca3, cb0, cb1, cb2, cb3);    // consume group 194
  FMA4G(na0, na1, na2, na3, nb0, nb1, nb2, nb3);    // consume group 195
#undef PREF
#undef FMA4G
#undef FMA16
#undef LDG4

  // Epilogue: + b1 (f32 add like ref), exact f32 IF-period loop, emit mask32
  if (bOK) {
    float4 bb = *(const float4*)&b1[hOut];
#pragma unroll
    for (int mi = 0; mi < 4; mi++) {
      int m = mBase + mi;
      float c4[4] = {acc[mi][0] + bb.x, acc[mi][1] + bb.y,
                     acc[mi][2] + bb.z, acc[mi][3] + bb.w};
      uint32_t mk4[4];
#pragma unroll
      for (int ni = 0; ni < 4; ni++) {
        float c = c4[ni];
        float v = 0.0f;
        int p = 0;
#pragma unroll 1
        for (int s = 1; s <= T_SIM; s++) {
          float h1 = v + c;                   // f32 add, as reference
          if (h1 >= 1.0f) { p = s; break; }
          v = h1;
        }
        uint32_t mk = 0;
        if (p) for (int s = p; s <= T_SIM; s += p) mk |= 1u << (s - 1);
        mk4[ni] = mk;
      }
      *(uint4*)&mb[(size_t)m * H_DIM + hOut] =
          make_uint4(mk4[0], mk4[1], mk4[2], mk4[3]);
    }
  }
}

// ---------------------------------------------------------------------------
// K2: SNN scan — proven 40 KB / 4-blocks-per-CU version (unchanged, ~125 us).
// LDS = W2T 32000 + pkS 7168 (+small) < 40960 -> 4 blocks/CU.
// Exec per entry: 1 b64 pk read + 1 b64 w read (both <=2-distinct,
// conflict-free) + ~4 VALU.
// Exactness: per (row,t,o) ascending-h single-accumulator gated fold —
// never-spiking h skipped (+0 identity), each step +w or +0 (select form;
// pads have mask=0). Overflow (>CAP) -> gated full scan, same order.
// ---------------------------------------------------------------------------
__global__ __launch_bounds__(320) void snn_scan(const uint32_t* __restrict__ mb,
                                                const float* __restrict__ W2,
                                                const float* __restrict__ b2,
                                                float* __restrict__ out) {
  __shared__ __align__(16) float W2T[H_DIM * D_OUT];  // [h][o], 32000 B
  __shared__ __align__(16) uint2 pkS[2][CAP];         // {h*40, mask}, 7168 B
  __shared__ int   lenS[2];
  __shared__ float b2f[D_OUT];
  float* c2s = (float*)&pkS[0][0];            // union: [r][t][o], 2560 B
  const int tid  = threadIdx.x;               // 0..319
  const int row0 = blockIdx.x * 2;

  if (tid < D_OUT) b2f[tid] = b2[tid];

  if (tid < 128) {
    // ---- Build (waves 0-1): ballot-compact mask words, ascending h ----
    const int r = tid >> 6, ln = tid & 63;
    const uint64_t lm = (1ull << ln) - 1ull;
    const uint32_t* mrow = mb + (size_t)(row0 + r) * H_DIM;
    uint32_t mv[13];
#pragma unroll
    for (int ch = 0; ch < 13; ++ch) {         // independent coalesced loads
      int h = ch * 64 + ln;
      mv[ch] = (h < H_DIM) ? mrow[h] : 0u;
    }
    int off = 0;
#pragma unroll
    for (int ch = 0; ch < 13; ++ch) {
      bool g = (mv[ch] != 0u);
      uint64_t bal = __ballot(g);
      int pos = off + __popcll(bal & lm);
      if (g && pos < CAP) {
        uint2 pk; pk.x = (uint32_t)((ch * 64 + ln) * 40); pk.y = mv[ch];
        pkS[r][pos] = pk;
      }
      off += __popcll(bal);
    }
    if (off <= CAP) {                         // self-pad to multiple of 64
      int lp = (off + 63) & ~63;              // <= CAP since off <= CAP
      int i = off + ln;
      if (i < lp) { pkS[r][i].x = 0u; pkS[r][i].y = 0u; }
    }
    if (ln == 0) lenS[r] = off;
  } else {
    // ---- W2T staging (waves 2-4): coalesced read, LDS scatter ----
    for (int e = tid - 128; e < H_DIM * D_OUT; e += 192) {
      int o = e / H_DIM, h = e - o * H_DIM;
      W2T[h * D_OUT + o] = W2[e];
    }
  }
  __syncthreads();

  // ---- Exec: wave j = o-pair, lanes (t, r); 2 LDS ops per entry ----
  float s0 = 0.0f, s1 = 0.0f;
  const int j = tid >> 6;                     // 0..4
  const int lane = tid & 63;
  const int t = lane & 31;
  const int r = lane >> 5;
  const bool ovf = (lenS[0] > CAP) || (lenS[1] > CAP);
  {
    if (!ovf) {
      const int Lpad = (lenS[r] + 63) & ~63;  // per-r trip count (divergent ok)
      const uint2* pp = pkS[r];
      const char* wbase = (const char*)W2T + 8 * j;
#pragma unroll 4
      for (int i = 0; i < Lpad; ++i) {
        uint2 pk = pp[i];                     // b64, 2-distinct broadcast
        float2 w = *(const float2*)(wbase + pk.x);  // b64, 2-distinct
        bool g = (pk.y >> t) & 1u;
        s0 += g ? w.x : 0.0f;                 // identical op to ref (+w / +0)
        s1 += g ? w.y : 0.0f;
      }
    } else {                                  // overflow fallback: gated scan
      const uint32_t* mrow = mb + (size_t)(row0 + r) * H_DIM;
      const uint32_t vbit = 1u << t;
      for (int h = 0; h < H_DIM; ++h) {
        uint32_t mk = mrow[h];
        float2 w = *(const float2*)&W2T[h * D_OUT + 2 * j];
        s0 += (mk & vbit) ? w.x : 0.0f;
        s1 += (mk & vbit) ? w.y : 0.0f;
      }
    }
  }
  __syncthreads();                            // all pk reads complete
  c2s[((r * T_SIM) + t) * D_OUT + 2 * j]     = s0;   // union region write
  c2s[((r * T_SIM) + t) * D_OUT + 2 * j + 1] = s1;
  __syncthreads();

  // ---- Layer-2 IF scan + spike count (exact f32 ref order) ----
  if (tid < 2 * D_OUT) {
    const int rr = tid / D_OUT, o = tid % D_OUT;
    const float bb = b2f[o];
    float v = 0.0f; int cnt = 0;
#pragma unroll
    for (int tt = 0; tt < T_SIM; ++tt) {
      float cur2 = c2s[((rr * T_SIM) + tt) * D_OUT + o] + bb;  // f32 add
      float h2 = v + cur2;                    // f32 add
      bool spk = (h2 >= 1.0f);
      cnt += spk ? 1 : 0;
      v = spk ? 0.0f : h2;
    }
    out[(size_t)(row0 + rr) * D_OUT + o] = (float)cnt;
  }
}

// ---------------------------------------------------------------------------
extern "C" void kernel_launch(void* const* d_in, const int* in_sizes, int n_in,
                              void* d_out, int out_size, void* d_ws, size_t ws_size,
                              hipStream_t stream) {
  const float* x  = (const float*)d_in[0];
  const float* W1 = (const float*)d_in[1];
  const float* b1 = (const float*)d_in[2];
  const float* W2 = (const float*)d_in[3];
  const float* b2 = (const float*)d_in[4];
  float* outp = (float*)d_out;

  float*    xfT  = (float*)d_ws;                    // 784*4096 f32 (12.85 MB)
  float*    W1T  = xfT + (size_t)D_IN * B_ROWS;     // 784*800  f32 ( 2.51 MB)
  uint32_t* mbuf = (uint32_t*)(W1T + (size_t)D_IN * H_DIM);  // B*H u32 (13.1 MB)

  gen_xfixed_T<<<dim3(16, 49), 256, 0, stream>>>(x, xfT);
  transpose_w1<<<(D_IN * H_DIM + 255) / 256, 256, 0, stream>>>(W1, W1T);

  dim3 g1(13, 64);                                  // 13 x 64 = 832 blocks
  gemm_masks<<<g1, 256, 0, stream>>>(xfT, W1T, b1, mbuf);

  snn_scan<<<B_ROWS / 2, 320, 0, stream>>>(mbuf, W2, b2, outp);
}

// Round 6
// 280.077 us; speedup vs baseline: 1.3527x; 1.3527x over previous
//
#include <hip/hip_runtime.h>
#include <stdint.h>

// Problem constants (fixed by setup_inputs; all tensors f32)
#define B_ROWS 4096
#define D_IN   784
#define H_DIM  800
#define D_OUT  10
#define T_SIM  32
#define N_ELEM (B_ROWS * D_IN)   // 3211264
#define CAP    448               // spiking-list cap/row (mean ~376, sd ~14)

// ---------------------------------------------------------------------------
// Bit-exact JAX threefry2x32 (key = PRNGKey(42) = {0, 42})
// ---------------------------------------------------------------------------
__device__ __forceinline__ void threefry2x32(uint32_t k0, uint32_t k1,
                                             uint32_t& x0, uint32_t& x1) {
  uint32_t ks0 = k0, ks1 = k1, ks2 = k0 ^ k1 ^ 0x1BD11BDAu;
  x0 += ks0; x1 += ks1;
#define TF_RND(r) { x0 += x1; x1 = (x1 << (r)) | (x1 >> (32 - (r))); x1 ^= x0; }
  TF_RND(13) TF_RND(15) TF_RND(26) TF_RND(6)
  x0 += ks1; x1 += ks2 + 1u;
  TF_RND(17) TF_RND(29) TF_RND(16) TF_RND(24)
  x0 += ks2; x1 += ks0 + 2u;
  TF_RND(13) TF_RND(15) TF_RND(26) TF_RND(6)
  x0 += ks0; x1 += ks1 + 3u;
  TF_RND(17) TF_RND(29) TF_RND(16) TF_RND(24)
  x0 += ks1; x1 += ks2 + 4u;
  TF_RND(13) TF_RND(15) TF_RND(26) TF_RND(6)
  x0 += ks2; x1 += ks0 + 5u;
#undef TF_RND
}

// ---------------------------------------------------------------------------
// K0a: x_fixed computed DIRECTLY in transposed layout xfT[k][m] (k-major).
// Same threefry counter i = m*784 + k -> bit-identical values.
// ---------------------------------------------------------------------------
__global__ __launch_bounds__(256) void gen_xfixed_T(const float* __restrict__ x,
                                                    float* __restrict__ xfT) {
  const int m = blockIdx.x * 256 + threadIdx.x;   // 0..4095
  const int kb = blockIdx.y * 16;                 // 0,16,..,768
#pragma unroll 1
  for (int kk = 0; kk < 16; ++kk) {
    const int k = kb + kk;
    const int i = m * D_IN + k;
    uint32_t c0 = 0u, c1 = (uint32_t)i;
    threefry2x32(0u, 42u, c0, c1);
    uint32_t bits = c0 ^ c1;
    float u = __uint_as_float((bits >> 9) | 0x3F800000u) - 1.0f;
    xfT[(size_t)k * B_ROWS + m] = (u < x[i]) ? 1.0f : 0.0f;
  }
}

// K0b: W1T[k][h] = W1[h][k] — bit-exact copy, 2.5 MB. Coalesced writes.
__global__ __launch_bounds__(256) void transpose_w1(const float* __restrict__ W1,
                                                    float* __restrict__ W1T) {
  const int idx = blockIdx.x * 256 + threadIdx.x;   // over k*800+h
  if (idx >= D_IN * H_DIM) return;
  const int k = idx / H_DIM;
  const int h = idx - k * H_DIM;
  W1T[idx] = W1[h * D_IN + k];
}

// ---------------------------------------------------------------------------
// K1 (R6): R4's proven 64x64 / 4x4 / 13-waves-per-CU core, with the staging
// machinery replaced by async global_load_lds (width 16) from the k-major
// xfT/W1T.  Removes per-thread register round-trip (2 dwordx4 + 8 ds_write
// per tile) and its waitcnt chains; 2 global_load_lds per wave per tile
// stage the whole 8 KB (A+B) tile.  LDS dest is linear (wave-uniform base +
// lane*16), source rows are m-/h-contiguous 256 B.  Double-buffered, ONE
// __syncthreads per K-tile (its vmcnt(0) drain completes the async loads).
// Read conflicts: A-frag 4 distinct 16B in distinct banks (free); B-frag
// 16 addrs over 32 banks = 2-way (free, m136).  LDS 16.4 KB, ~56 VGPR.
// Out-of-tile h (block x=12, h>=800): garbage staged/computed, never
// written (hOut<800 guard) — reads stay inside the workspace allocation.
// Exactness: per output single f32 acc, strict ascending-k fma chain,
// identical epilogue -> bit-identical (absmax 0.0).
// ---------------------------------------------------------------------------
#define BK 16

#define GL2LDS(g, l) __builtin_amdgcn_global_load_lds(                      \
    (const __attribute__((address_space(1))) void*)(g),                     \
    (__attribute__((address_space(3))) void*)(l), 16, 0, 0)

__global__ __launch_bounds__(256) void gemm_masks(const float* __restrict__ xfT,
                                                  const float* __restrict__ W1T,
                                                  const float* __restrict__ b1,
                                                  uint32_t* __restrict__ mb) {
  __shared__ __align__(16) float As[2][BK][64];   // 2 x 4 KB, linear
  __shared__ __align__(16) float Bs[2][BK][64];   // 2 x 4 KB, linear
  const int t  = threadIdx.x;        // 0..255
  const int tx = t & 15, ty = t >> 4;
  const int m0 = blockIdx.y * 64;
  const int n0 = blockIdx.x * 64;

  // staging geometry: wave w stages rows 4w..4w+3 of each 16x64 tile
  const int w = t >> 6;              // wave 0..3
  const int l = t & 63;              // lane
  const int skk = 4 * w + (l >> 4);  // source row 0..15
  const int sm  = (l & 15) * 4;      // source col group
  const float* gA = xfT + (size_t)skk * B_ROWS + m0 + sm;  // + tt*16*4096
  const float* gB = W1T + (size_t)skk * H_DIM + n0 + sm;   // + tt*16*800

#define STAGE(buf, tt) {                                                    \
    GL2LDS(gA + (size_t)(tt) * BK * B_ROWS, &As[buf][4 * w][0]);            \
    GL2LDS(gB + (size_t)(tt) * BK * H_DIM,  &Bs[buf][4 * w][0]); }

  STAGE(0, 0);
  __syncthreads();                       // vmcnt(0) drain -> tile 0 ready

  float acc[4][4] = {};
  const int NT = D_IN / BK;              // 49 tiles, ascending k
#pragma unroll 1
  for (int tt = 0; tt < NT; ++tt) {
    const int cur = tt & 1;
    if (tt + 1 < NT) STAGE(cur ^ 1, tt + 1);   // async into other buffer
#pragma unroll
    for (int kk = 0; kk < BK; kk++) {    // strict ascending k, single acc
      float4 av = *(const float4*)&As[cur][kk][ty * 4];   // ds_read_b128
      float4 bv = *(const float4*)&Bs[cur][kk][tx * 4];   // ds_read_b128
      float a[4] = {av.x, av.y, av.z, av.w};
      float b[4] = {bv.x, bv.y, bv.z, bv.w};
#pragma unroll
      for (int mi = 0; mi < 4; mi++)
#pragma unroll
        for (int ni = 0; ni < 4; ni++)
          acc[mi][ni] = __builtin_fmaf(a[mi], b[ni], acc[mi][ni]);
    }
    __syncthreads();                     // ONE barrier per tile:
    // separates (a) this iter's reads of buf[cur] from next iter's stage
    // into buf[cur], and (b) drains the async stage of buf[cur^1].
  }
#undef STAGE

  // Epilogue: + b1 (f32 add like ref), exact f32 IF-period loop, emit mask32
  const int hOut = n0 + tx * 4;          // multiple of 4
  if (hOut < H_DIM) {
    float4 bb = *(const float4*)&b1[hOut];
#pragma unroll
    for (int mi = 0; mi < 4; mi++) {
      int m = m0 + ty * 4 + mi;
      float c4[4] = {acc[mi][0] + bb.x, acc[mi][1] + bb.y,
                     acc[mi][2] + bb.z, acc[mi][3] + bb.w};
      uint32_t mk4[4];
#pragma unroll
      for (int ni = 0; ni < 4; ni++) {
        float c = c4[ni];
        float v = 0.0f;
        int p = 0;
#pragma unroll 1
        for (int s = 1; s <= T_SIM; s++) {
          float h1 = v + c;                   // f32 add, as reference
          if (h1 >= 1.0f) { p = s; break; }
          v = h1;
        }
        uint32_t mk = 0;
        if (p) for (int s = p; s <= T_SIM; s += p) mk |= 1u << (s - 1);
        mk4[ni] = mk;
      }
      *(uint4*)&mb[(size_t)m * H_DIM + hOut] =
          make_uint4(mk4[0], mk4[1], mk4[2], mk4[3]);
    }
  }
}

// ---------------------------------------------------------------------------
// K2: SNN scan — proven 40 KB / 4-blocks-per-CU version.  Only change vs R4:
// exec-loop unroll 4 -> 8 (scheduling only; the s0/s1 dependency chain
// enforces ascending-i order regardless, so arithmetic is identical).
// ---------------------------------------------------------------------------
__global__ __launch_bounds__(320) void snn_scan(const uint32_t* __restrict__ mb,
                                                const float* __restrict__ W2,
                                                const float* __restrict__ b2,
                                                float* __restrict__ out) {
  __shared__ __align__(16) float W2T[H_DIM * D_OUT];  // [h][o], 32000 B
  __shared__ __align__(16) uint2 pkS[2][CAP];         // {h*40, mask}, 7168 B
  __shared__ int   lenS[2];
  __shared__ float b2f[D_OUT];
  float* c2s = (float*)&pkS[0][0];            // union: [r][t][o], 2560 B
  const int tid  = threadIdx.x;               // 0..319
  const int row0 = blockIdx.x * 2;

  if (tid < D_OUT) b2f[tid] = b2[tid];

  if (tid < 128) {
    // ---- Build (waves 0-1): ballot-compact mask words, ascending h ----
    const int r = tid >> 6, ln = tid & 63;
    const uint64_t lm = (1ull << ln) - 1ull;
    const uint32_t* mrow = mb + (size_t)(row0 + r) * H_DIM;
    uint32_t mv[13];
#pragma unroll
    for (int ch = 0; ch < 13; ++ch) {         // independent coalesced loads
      int h = ch * 64 + ln;
      mv[ch] = (h < H_DIM) ? mrow[h] : 0u;
    }
    int off = 0;
#pragma unroll
    for (int ch = 0; ch < 13; ++ch) {
      bool g = (mv[ch] != 0u);
      uint64_t bal = __ballot(g);
      int pos = off + __popcll(bal & lm);
      if (g && pos < CAP) {
        uint2 pk; pk.x = (uint32_t)((ch * 64 + ln) * 40); pk.y = mv[ch];
        pkS[r][pos] = pk;
      }
      off += __popcll(bal);
    }
    if (off <= CAP) {                         // self-pad to multiple of 64
      int lp = (off + 63) & ~63;              // <= CAP since off <= CAP
      int i = off + ln;
      if (i < lp) { pkS[r][i].x = 0u; pkS[r][i].y = 0u; }
    }
    if (ln == 0) lenS[r] = off;
  } else {
    // ---- W2T staging (waves 2-4): coalesced read, LDS scatter ----
    for (int e = tid - 128; e < H_DIM * D_OUT; e += 192) {
      int o = e / H_DIM, h = e - o * H_DIM;
      W2T[h * D_OUT + o] = W2[e];
    }
  }
  __syncthreads();

  // ---- Exec: wave j = o-pair, lanes (t, r); 2 LDS ops per entry ----
  float s0 = 0.0f, s1 = 0.0f;
  const int j = tid >> 6;                     // 0..4
  const int lane = tid & 63;
  const int t = lane & 31;
  const int r = lane >> 5;
  const bool ovf = (lenS[0] > CAP) || (lenS[1] > CAP);
  {
    if (!ovf) {
      const int Lpad = (lenS[r] + 63) & ~63;  // per-r trip count (divergent ok)
      const uint2* pp = pkS[r];
      const char* wbase = (const char*)W2T + 8 * j;
#pragma unroll 8
      for (int i = 0; i < Lpad; ++i) {
        uint2 pk = pp[i];                     // b64, 2-distinct broadcast
        float2 w = *(const float2*)(wbase + pk.x);  // b64, 2-distinct
        bool g = (pk.y >> t) & 1u;
        s0 += g ? w.x : 0.0f;                 // identical op to ref (+w / +0)
        s1 += g ? w.y : 0.0f;
      }
    } else {                                  // overflow fallback: gated scan
      const uint32_t* mrow = mb + (size_t)(row0 + r) * H_DIM;
      const uint32_t vbit = 1u << t;
      for (int h = 0; h < H_DIM; ++h) {
        uint32_t mk = mrow[h];
        float2 w = *(const float2*)&W2T[h * D_OUT + 2 * j];
        s0 += (mk & vbit) ? w.x : 0.0f;
        s1 += (mk & vbit) ? w.y : 0.0f;
      }
    }
  }
  __syncthreads();                            // all pk reads complete
  c2s[((r * T_SIM) + t) * D_OUT + 2 * j]     = s0;   // union region write
  c2s[((r * T_SIM) + t) * D_OUT + 2 * j + 1] = s1;
  __syncthreads();

  // ---- Layer-2 IF scan + spike count (exact f32 ref order) ----
  if (tid < 2 * D_OUT) {
    const int rr = tid / D_OUT, o = tid % D_OUT;
    const float bb = b2f[o];
    float v = 0.0f; int cnt = 0;
#pragma unroll
    for (int tt = 0; tt < T_SIM; ++tt) {
      float cur2 = c2s[((rr * T_SIM) + tt) * D_OUT + o] + bb;  // f32 add
      float h2 = v + cur2;                    // f32 add
      bool spk = (h2 >= 1.0f);
      cnt += spk ? 1 : 0;
      v = spk ? 0.0f : h2;
    }
    out[(size_t)(row0 + rr) * D_OUT + o] = (float)cnt;
  }
}

// ---------------------------------------------------------------------------
extern "C" void kernel_launch(void* const* d_in, const int* in_sizes, int n_in,
                              void* d_out, int out_size, void* d_ws, size_t ws_size,
                              hipStream_t stream) {
  const float* x  = (const float*)d_in[0];
  const float* W1 = (const float*)d_in[1];
  const float* b1 = (const float*)d_in[2];
  const float* W2 = (const float*)d_in[3];
  const float* b2 = (const float*)d_in[4];
  float* outp = (float*)d_out;

  float*    xfT  = (float*)d_ws;                    // 784*4096 f32 (12.85 MB)
  float*    W1T  = xfT + (size_t)D_IN * B_ROWS;     // 784*800  f32 ( 2.51 MB)
  uint32_t* mbuf = (uint32_t*)(W1T + (size_t)D_IN * H_DIM);  // B*H u32 (13.1 MB)

  gen_xfixed_T<<<dim3(16, 49), 256, 0, stream>>>(x, xfT);
  transpose_w1<<<(D_IN * H_DIM + 255) / 256, 256, 0, stream>>>(W1, W1T);

  dim3 g1(13, 64);                                  // 13 x 64 = 832 blocks
  gemm_masks<<<g1, 256, 0, stream>>>(xfT, W1T, b1, mbuf);

  snn_scan<<<B_ROWS / 2, 320, 0, stream>>>(mbuf, W2, b2, outp);
}